// Round 9
// baseline (31225.354 us; speedup 1.0000x reference)
//
#include <hip/hip_runtime.h>

#define Tn     512
#define Dn     64
#define Hn     512
#define BB     64              // batch rows per group/block
#define NC     8               // col-split blocks per group (64 h-cols each)
#define NGRP   32              // 2048 / BB
#define NKS    20              // K = 640 / 32

typedef __attribute__((ext_vector_type(8))) short  short8;   // 8 bf16 (4 VGPRs)
typedef __attribute__((ext_vector_type(4))) float  floatx4;  // MFMA acc

__device__ __forceinline__ unsigned short f2bf(float f) {
  unsigned u = __float_as_uint(f);
  unsigned r = u + 0x7fffu + ((u >> 16) & 1u);
  return (unsigned short)(r >> 16);
}
__device__ __forceinline__ float frcp(float x) { return __builtin_amdgcn_rcpf(x); }
__device__ __forceinline__ float sigm(float x) { return frcp(1.f + __expf(-x)); }
__device__ __forceinline__ float tanhfast(float y) {
  float a = fabsf(y);
  float e = __expf(-2.f * a);
  float m = 1.f - 2.f * e * frcp(1.f + e);
  return copysignf(m, y);
}
__device__ __forceinline__ short8 pack8(float4 a, float4 b) {
  union { unsigned short us[8]; short8 v; } pk;
  pk.us[0] = f2bf(a.x); pk.us[1] = f2bf(a.y); pk.us[2] = f2bf(a.z); pk.us[3] = f2bf(a.w);
  pk.us[4] = f2bf(b.x); pk.us[5] = f2bf(b.y); pk.us[6] = f2bf(b.z); pk.us[7] = f2bf(b.w);
  return pk.v;
}

// ---------------------------------------------------------------------------
// Prep: pack W into per-(cc, ct, kh)-wave B-fragment order, bf16.
// flat = ((((cc*4+ct)*2+kh)*10 + ksl)*3 + g)*64 + lane
// col n = g*512 + cc*64 + ct*16 + (lane&15); k = (kh*10+ksl)*32 + (lane>>4)*8
// k<128 -> W_ih, else W_hh. Total 122880 frags * 16 B = 1.97 MB.
// ---------------------------------------------------------------------------
__global__ __launch_bounds__(256) void cru_prep(
    const float* __restrict__ W_ih, const float* __restrict__ W_hh,
    short8* __restrict__ WB)
{
  int idx = blockIdx.x * 256 + threadIdx.x;
  if (idx >= NC * 4 * 2 * 10 * 3 * 64) return;
  int lane = idx & 63;
  int rem  = idx >> 6;
  int g    = rem % 3;  rem /= 3;
  int ksl  = rem % 10; rem /= 10;
  int kh   = rem & 1;  rem >>= 1;
  int ct   = rem & 3;
  int cc   = rem >> 2;
  int n  = g * 512 + cc * 64 + ct * 16 + (lane & 15);
  int k0 = (kh * 10 + ksl) * 32 + (lane >> 4) * 8;
  const float* src = (k0 < 128) ? (W_ih + (size_t)n * 128 + k0)
                                : (W_hh + (size_t)n * 512 + (k0 - 128));
  float4 x0 = ((const float4*)src)[0];
  float4 x1 = ((const float4*)src)[1];
  WB[idx] = pack8(x0, x1);
}

// zero the row-major h-exchange buffer (both parities) and the flags
__global__ __launch_bounds__(256) void cru_zero(float4* __restrict__ hx, int* __restrict__ flg)
{
  int idx = blockIdx.x * 256 + threadIdx.x;
  if (idx < 2 * 2048 * Hn / 8) hx[idx] = make_float4(0.f, 0.f, 0.f, 0.f);  // 4 MB
  if (idx < NGRP * 16) flg[idx] = 0;
}

// ---------------------------------------------------------------------------
// Main: 256 blocks x 512 threads (8 waves), 1 block/CU (LDS 145.9 KB), all
// resident. Block (grp, cc) owns batch rows [grp*64,+64) and h-cols
// [cc*64,+64). Wave (ct,kh): col-tile ct, K-half kh, all 4 M-tiles. Weights:
// 30 frags = 120 VGPRs/wave, persistent. kh halves combine via LDS.
// h exchanged per step via ROW-MAJOR bf16 buffer hx[par][b][j] (plain scalar
// writes; reader re-gathers A-frags with R0-verified staging math), parity
// double-buffered, per-block flags w/ acquire spin (group-mates same XCD).
// ---------------------------------------------------------------------------
__global__ __launch_bounds__(512, 2) void cru_main(
    const float* __restrict__ values, const float* __restrict__ maskp,
    const float* __restrict__ tsp,
    const float* __restrict__ b_ih, const float* __restrict__ b_hh,
    const float* __restrict__ W_decay, const float* __restrict__ b_decay,
    const float* __restrict__ W_head,
    const short8* __restrict__ WB,
    unsigned short* __restrict__ hx,    // [par][2048][512] bf16, 4 MB
    int* __restrict__ flg,              // [grp][16] step-completed flags
    float* __restrict__ part)           // [NC][2048][8] head partials
{
  __shared__ short8  apk[4 * NKS * 64];   // A frags [mt][ks][lane], 80 KB
  __shared__ floatx4 xacc[4 * 12 * 64];   // kh=1 partial accs, 48 KB
  __shared__ float   hfin[BB][68];        // fp32 master h, 17.4 KB
  __shared__ float   sdt[BB];

  const int tid  = threadIdx.x;
  const int gid  = blockIdx.x;
  const int grp  = gid & (NGRP - 1);      // mates gid = grp+32*cc -> same XCD (mod 8)
  const int cc   = gid >> 5;
  const int b0   = grp * BB;
  const int w    = tid >> 6;
  const int lane = tid & 63;
  const int quad = lane >> 4;
  const int lc   = lane & 15;
  const int ct   = w & 3;
  const int kh   = w >> 2;

  // ---- persistent weights: 30 frags = 120 VGPRs/wave ----
  short8 Bf[10][3];
  {
    const short8* wb = WB + (size_t)(((cc * 4 + ct) * 2 + kh) * 30) * 64 + lane;
    #pragma unroll
    for (int ksl = 0; ksl < 10; ++ksl)
      #pragma unroll
      for (int g = 0; g < 3; ++g)
        Bf[ksl][g] = wb[(ksl * 3 + g) * 64];
  }

  // per-thread gate constants for h-col j = cc*64 + ct*16 + lc (used by kh=0)
  const int   j    = cc * 64 + ct * 16 + lc;
  const int   jl   = ct * 16 + lc;
  const float bRv  = b_ih[j]        + b_hh[j];
  const float bZv  = b_ih[512 + j]  + b_hh[512 + j];
  const float bINv = b_ih[1024 + j];
  const float bHNv = b_hh[1024 + j];
  const float wdcv = W_decay[j];
  const float bdcv = b_decay[j];

  // x staging: 2 slots/thread (4 mt x 4 ks x 64 lanes = 1024 slots)
  const float* xb[2];
  int apk_x[2];
  #pragma unroll
  for (int s = 0; s < 2; ++s) {
    int sidx = s * 512 + tid;
    int mt_s = sidx >> 8, r = sidx & 255, ks_s = r >> 6, ln = r & 63;
    int m  = mt_s * 16 + (ln & 15);
    int kg = ks_s * 32 + (ln >> 4) * 8;
    xb[s] = (kg < 64 ? values + (size_t)(b0 + m) * Tn * Dn + kg
                     : maskp  + (size_t)(b0 + m) * Tn * Dn + (kg - 64));
    apk_x[s] = (mt_s * NKS + ks_s) * 64 + ln;
  }
  short8 xp0 = pack8(((const float4*)xb[0])[0], ((const float4*)xb[0])[1]);
  short8 xp1 = pack8(((const float4*)xb[1])[0], ((const float4*)xb[1])[1]);

  // zero master h
  for (int i = tid; i < BB * 68; i += 512) (&hfin[0][0])[i] = 0.f;

  int* myflag = flg + grp * 16 + cc;

  for (int t = 0; t < Tn; ++t) {
    // ---- wait for all group-mates to finish step t-1 ----
    if (t > 0 && tid < 8) {
      const int* fp = flg + grp * 16 + tid;
      int sp = 0;
      while (__hip_atomic_load(fp, __ATOMIC_ACQUIRE, __HIP_MEMORY_SCOPE_AGENT) < t
             && ++sp < (1 << 16))
        __builtin_amdgcn_s_sleep(8);
    }
    __syncthreads();

    // ---- stage x (prefetched+packed last step) ----
    apk[apk_x[0]] = xp0;
    apk[apk_x[1]] = xp1;
    if (tid < BB && t + 1 < Tn) {
      size_t rbm = (size_t)(b0 + tid) * Tn + t;
      sdt[tid] = tsp[rbm + 1] - tsp[rbm];
    }
    // ---- gather h(t-1) A-frags from row-major hx (R0-verified staging math):
    //      slot(mt,ksh,ln): m = mt*16+(ln&15), k = ksh*32+(ln>>4)*8, 8 contig bf16
    {
      const unsigned short* hsrc = hx + (size_t)((t + 1) & 1) * (2048 * Hn)
                                      + (size_t)b0 * Hn;
      #pragma unroll
      for (int i = 0; i < 8; ++i) {
        int idx = tid + i * 512;                      // 0..4095
        int mt = idx >> 10, r = idx & 1023, ksh = r >> 6, ln = r & 63;
        const unsigned short* p = hsrc + (size_t)(mt * 16 + (ln & 15)) * Hn
                                       + ksh * 32 + (ln >> 4) * 8;
        apk[(mt * NKS + 4 + ksh) * 64 + ln] = *(const short8*)p;
      }
    }
    __syncthreads();

    // ---- K-loop: 120 MFMAs/wave, weights in registers, static kh split ----
    floatx4 aR[4], aZ[4], aIN[4], aHN[4];
    #pragma unroll
    for (int mt = 0; mt < 4; ++mt) {
      aR[mt]  = (floatx4){0.f,0.f,0.f,0.f};
      aZ[mt]  = (floatx4){0.f,0.f,0.f,0.f};
      aIN[mt] = (floatx4){0.f,0.f,0.f,0.f};
      aHN[mt] = (floatx4){0.f,0.f,0.f,0.f};
    }
    if (kh == 0) {
      #pragma unroll
      for (int ksl = 0; ksl < 10; ++ksl) {
        short8 A[4];
        #pragma unroll
        for (int mt = 0; mt < 4; ++mt) A[mt] = apk[(mt * NKS + ksl) * 64 + lane];
        #pragma unroll
        for (int mt = 0; mt < 4; ++mt) {
          aR[mt] = __builtin_amdgcn_mfma_f32_16x16x32_bf16(A[mt], Bf[ksl][0], aR[mt], 0, 0, 0);
          aZ[mt] = __builtin_amdgcn_mfma_f32_16x16x32_bf16(A[mt], Bf[ksl][1], aZ[mt], 0, 0, 0);
          if (ksl < 4)
            aIN[mt] = __builtin_amdgcn_mfma_f32_16x16x32_bf16(A[mt], Bf[ksl][2], aIN[mt], 0, 0, 0);
          else
            aHN[mt] = __builtin_amdgcn_mfma_f32_16x16x32_bf16(A[mt], Bf[ksl][2], aHN[mt], 0, 0, 0);
        }
      }
    } else {
      #pragma unroll
      for (int ksl = 0; ksl < 10; ++ksl) {
        short8 A[4];
        #pragma unroll
        for (int mt = 0; mt < 4; ++mt) A[mt] = apk[(mt * NKS + 10 + ksl) * 64 + lane];
        #pragma unroll
        for (int mt = 0; mt < 4; ++mt) {
          aR[mt]  = __builtin_amdgcn_mfma_f32_16x16x32_bf16(A[mt], Bf[ksl][0], aR[mt], 0, 0, 0);
          aZ[mt]  = __builtin_amdgcn_mfma_f32_16x16x32_bf16(A[mt], Bf[ksl][1], aZ[mt], 0, 0, 0);
          aHN[mt] = __builtin_amdgcn_mfma_f32_16x16x32_bf16(A[mt], Bf[ksl][2], aHN[mt], 0, 0, 0);
        }
      }
    }

    // ---- prefetch next step's x ----
    xb[0] += Dn; xb[1] += Dn;
    if (t + 1 < Tn) {
      xp0 = pack8(((const float4*)xb[0])[0], ((const float4*)xb[0])[1]);
      xp1 = pack8(((const float4*)xb[1])[0], ((const float4*)xb[1])[1]);
    }

    // ---- kh=1: publish partial accs ----
    if (kh == 1) {
      #pragma unroll
      for (int mt = 0; mt < 4; ++mt) {
        xacc[(ct * 12 + mt * 3 + 0) * 64 + lane] = aR[mt];
        xacc[(ct * 12 + mt * 3 + 1) * 64 + lane] = aZ[mt];
        xacc[(ct * 12 + mt * 3 + 2) * 64 + lane] = aHN[mt];
      }
    }
    __syncthreads();

    // ---- kh=0: combine halves, gates, h update, decay fold, h store ----
    const bool last = (t == Tn - 1);
    if (kh == 0) {
      unsigned short* hdst = hx + (size_t)(t & 1) * (2048 * Hn);
      #pragma unroll
      for (int mt = 0; mt < 4; ++mt) {
        floatx4 R  = aR[mt]  + xacc[(ct * 12 + mt * 3 + 0) * 64 + lane];
        floatx4 Z  = aZ[mt]  + xacc[(ct * 12 + mt * 3 + 1) * 64 + lane];
        floatx4 HN = aHN[mt] + xacc[(ct * 12 + mt * 3 + 2) * 64 + lane];
        #pragma unroll
        for (int q = 0; q < 4; ++q) {
          int m = mt * 16 + quad * 4 + q;
          float r  = sigm(R[q] + bRv);
          float z  = sigm(Z[q] + bZv);
          float nn = tanhfast(aIN[mt][q] + bINv + r * (HN[q] + bHNv));
          float h  = (1.f - z) * nn + z * hfin[m][jl];
          if (!last) {
            float pre = fmaf(sdt[m], wdcv, bdcv);
            h *= frcp(1.f + __expf(pre));              // exp(-softplus(pre))
            hdst[(size_t)(b0 + m) * Hn + j] = f2bf(h); // plain row-major store
          }
          hfin[m][jl] = h;
        }
      }
    }

    // ---- release h(t) ----
    if (!last) {
      __threadfence();
      __syncthreads();
      if (tid == 0)
        __hip_atomic_store(myflag, t + 1, __ATOMIC_RELEASE, __HIP_MEMORY_SCOPE_AGENT);
    } else {
      __syncthreads();   // hfin visible for head
    }
  }

  // ---- head partial: 64-col slice of h_T . W_head ----
  {
    int b = tid >> 3, nt2 = tid & 7;
    float a = 0.f;
    const float* wh = W_head + (size_t)nt2 * Hn + cc * 64;
    #pragma unroll 16
    for (int k2 = 0; k2 < 64; ++k2) a = fmaf(hfin[b][k2], wh[k2], a);
    part[((size_t)cc * 2048 + b0 + b) * 8 + nt2] = a;
  }
}

__global__ __launch_bounds__(256) void cru_head(
    const float* __restrict__ part, const float* __restrict__ b_head,
    float* __restrict__ out)
{
  int i = blockIdx.x * 256 + threadIdx.x;    // 2048*8 = 16384
  if (i >= 2048 * 8) return;
  float a = b_head[i & 7];
  #pragma unroll
  for (int c = 0; c < NC; ++c) a += part[(size_t)c * 16384 + i];
  out[i] = a;
}

extern "C" void kernel_launch(void* const* d_in, const int* in_sizes, int n_in,
                              void* d_out, int out_size, void* d_ws, size_t ws_size,
                              hipStream_t stream)
{
  const float* values  = (const float*)d_in[0];
  const float* mask    = (const float*)d_in[1];
  const float* tsp     = (const float*)d_in[2];
  const float* W_ih    = (const float*)d_in[3];
  const float* W_hh    = (const float*)d_in[4];
  const float* b_ih    = (const float*)d_in[5];
  const float* b_hh    = (const float*)d_in[6];
  const float* W_decay = (const float*)d_in[7];
  const float* b_decay = (const float*)d_in[8];
  const float* W_head  = (const float*)d_in[9];
  const float* b_head  = (const float*)d_in[10];
  float* out = (float*)d_out;

  char* ws = (char*)d_ws;
  short8*         WB   = (short8*)ws;                          // 1.97 MB
  unsigned short* hx   = (unsigned short*)(ws + (2u << 20));   // 4 MB row-major h
  float*          part = (float*)(ws + (6u << 20));            // 512 KB
  int*            flgp = (int*)(ws + (6u << 20) + (1u << 19)); // 2 KB

  int nfrag_total = NC * 4 * 2 * 10 * 3 * 64;                  // 122880
  cru_prep<<<(nfrag_total + 255) / 256, 256, 0, stream>>>(W_ih, W_hh, WB);
  cru_zero<<<1024, 256, 0, stream>>>((float4*)hx, flgp);
  cru_main<<<NC * NGRP, 512, 0, stream>>>(values, mask, tsp, b_ih, b_hh,
      W_decay, b_decay, W_head, WB, hx, flgp, part);
  cru_head<<<64, 256, 0, stream>>>(part, b_head, out);
}

// Round 10
// 5995.065 us; speedup vs baseline: 5.2085x; 5.2085x over previous
//
#include <hip/hip_runtime.h>

#define Tn     512
#define Dn     64
#define Hn     512
#define BB     64              // batch rows per group/block
#define NC     8               // col-split blocks per group (64 h-cols each)
#define NGRP   32              // 2048 / BB
#define NKS    20              // K = 640 / 32

typedef __attribute__((ext_vector_type(8))) short  short8;   // 8 bf16 (4 VGPRs)
typedef __attribute__((ext_vector_type(4))) float  floatx4;  // MFMA acc

__device__ __forceinline__ unsigned short f2bf(float f) {
  unsigned u = __float_as_uint(f);
  unsigned r = u + 0x7fffu + ((u >> 16) & 1u);
  return (unsigned short)(r >> 16);
}
__device__ __forceinline__ float frcp(float x) { return __builtin_amdgcn_rcpf(x); }
__device__ __forceinline__ float sigm(float x) { return frcp(1.f + __expf(-x)); }
__device__ __forceinline__ float tanhfast(float y) {
  float a = fabsf(y);
  float e = __expf(-2.f * a);
  float m = 1.f - 2.f * e * frcp(1.f + e);
  return copysignf(m, y);
}
__device__ __forceinline__ short8 pack8(float4 a, float4 b) {
  union { unsigned short us[8]; short8 v; } pk;
  pk.us[0] = f2bf(a.x); pk.us[1] = f2bf(a.y); pk.us[2] = f2bf(a.z); pk.us[3] = f2bf(a.w);
  pk.us[4] = f2bf(b.x); pk.us[5] = f2bf(b.y); pk.us[6] = f2bf(b.z); pk.us[7] = f2bf(b.w);
  return pk.v;
}

// ---------------------------------------------------------------------------
// Prep: pack W into per-(cc, ct, kh)-wave B-fragment order, bf16. (unchanged)
// ---------------------------------------------------------------------------
__global__ __launch_bounds__(256) void cru_prep(
    const float* __restrict__ W_ih, const float* __restrict__ W_hh,
    short8* __restrict__ WB)
{
  int idx = blockIdx.x * 256 + threadIdx.x;
  if (idx >= NC * 4 * 2 * 10 * 3 * 64) return;
  int lane = idx & 63;
  int rem  = idx >> 6;
  int g    = rem % 3;  rem /= 3;
  int ksl  = rem % 10; rem /= 10;
  int kh   = rem & 1;  rem >>= 1;
  int ct   = rem & 3;
  int cc   = rem >> 2;
  int n  = g * 512 + cc * 64 + ct * 16 + (lane & 15);
  int k0 = (kh * 10 + ksl) * 32 + (lane >> 4) * 8;
  const float* src = (k0 < 128) ? (W_ih + (size_t)n * 128 + k0)
                                : (W_hh + (size_t)n * 512 + (k0 - 128));
  float4 x0 = ((const float4*)src)[0];
  float4 x1 = ((const float4*)src)[1];
  WB[idx] = pack8(x0, x1);
}

// zero the flags (hx needs no zeroing: t=0 zeroes apk h-slots in LDS)
__global__ __launch_bounds__(256) void cru_zero(int* __restrict__ flg)
{
  int idx = blockIdx.x * 256 + threadIdx.x;
  if (idx < NGRP * 16) flg[idx] = 0;
}

// ---------------------------------------------------------------------------
// Main: 256 blocks x 512 threads (8 waves), 1 block/CU, all resident.
// Structure identical to the PASSING R9 kernel except the exchange protocol:
// h / flags move via RELAXED agent-scope atomics (sc0 sc1 memops, NO
// buffer_wbl2 / buffer_inv cache-maintenance per step — that was the 60us/step
// cost: WRITE_SIZE 5.4GB of forced L2 writebacks). Ordering comes from
// __syncthreads (drains vmcnt) + data dependence.
// ---------------------------------------------------------------------------
__global__ __launch_bounds__(512, 2) void cru_main(
    const float* __restrict__ values, const float* __restrict__ maskp,
    const float* __restrict__ tsp,
    const float* __restrict__ b_ih, const float* __restrict__ b_hh,
    const float* __restrict__ W_decay, const float* __restrict__ b_decay,
    const float* __restrict__ W_head,
    const short8* __restrict__ WB,
    unsigned long long* __restrict__ hx64, // [par][2048][512] bf16 as u64, 4 MB
    int* __restrict__ flg,                 // [grp][16] step-completed flags
    float* __restrict__ part)              // [NC][2048][8] head partials
{
  __shared__ short8  apk[4 * NKS * 64];   // A frags [mt][ks][lane], 80 KB
  __shared__ floatx4 xacc[4 * 12 * 64];   // kh=1 partial accs, 48 KB
  __shared__ float   hfin[BB][68];        // fp32 master h (decayed), 17.4 KB
  __shared__ float   sdt[BB];

  const int tid  = threadIdx.x;
  const int gid  = blockIdx.x;
  const int grp  = gid & (NGRP - 1);
  const int cc   = gid >> 5;
  const int b0   = grp * BB;
  const int w    = tid >> 6;
  const int lane = tid & 63;
  const int quad = lane >> 4;
  const int lc   = lane & 15;
  const int ct   = w & 3;
  const int kh   = w >> 2;

  // ---- persistent weights: 30 frags = 120 VGPRs/wave ----
  short8 Bf[10][3];
  {
    const short8* wb = WB + (size_t)(((cc * 4 + ct) * 2 + kh) * 30) * 64 + lane;
    #pragma unroll
    for (int ksl = 0; ksl < 10; ++ksl)
      #pragma unroll
      for (int g = 0; g < 3; ++g)
        Bf[ksl][g] = wb[(ksl * 3 + g) * 64];
  }

  // per-thread gate constants for h-col j = cc*64 + ct*16 + lc (used by kh=0)
  const int   j    = cc * 64 + ct * 16 + lc;
  const int   jl   = ct * 16 + lc;
  const float bRv  = b_ih[j]        + b_hh[j];
  const float bZv  = b_ih[512 + j]  + b_hh[512 + j];
  const float bINv = b_ih[1024 + j];
  const float bHNv = b_hh[1024 + j];
  const float wdcv = W_decay[j];
  const float bdcv = b_decay[j];

  // x staging: 2 slots/thread (4 mt x 4 ks x 64 lanes = 1024 slots)
  const float* xb[2];
  int apk_x[2];
  #pragma unroll
  for (int s = 0; s < 2; ++s) {
    int sidx = s * 512 + tid;
    int mt_s = sidx >> 8, r = sidx & 255, ks_s = r >> 6, ln = r & 63;
    int m  = mt_s * 16 + (ln & 15);
    int kg = ks_s * 32 + (ln >> 4) * 8;
    xb[s] = (kg < 64 ? values + (size_t)(b0 + m) * Tn * Dn + kg
                     : maskp  + (size_t)(b0 + m) * Tn * Dn + (kg - 64));
    apk_x[s] = (mt_s * NKS + ks_s) * 64 + ln;
  }
  short8 xp0 = pack8(((const float4*)xb[0])[0], ((const float4*)xb[0])[1]);
  short8 xp1 = pack8(((const float4*)xb[1])[0], ((const float4*)xb[1])[1]);

  // zero master h
  for (int i = tid; i < BB * 68; i += 512) (&hfin[0][0])[i] = 0.f;

  int* myflag = flg + grp * 16 + cc;

  // pack/store geometry for the cooperative h-publish (all 512 threads)
  const int pr  = tid >> 3;            // row 0..63
  const int pc0 = (tid & 7) * 8;       // local col 0,8,..,56

  for (int t = 0; t < Tn; ++t) {
    // ---- wait for all group-mates to finish step t-1 (relaxed polls) ----
    if (t > 0 && tid < 8) {
      const int* fp = flg + grp * 16 + tid;
      int sp = 0;
      while (__hip_atomic_load(fp, __ATOMIC_RELAXED, __HIP_MEMORY_SCOPE_AGENT) < t
             && ++sp < (1 << 15))
        __builtin_amdgcn_s_sleep(2);
    }
    __syncthreads();

    // ---- stage x (prefetched+packed last step) ----
    apk[apk_x[0]] = xp0;
    apk[apk_x[1]] = xp1;
    if (tid < BB && t + 1 < Tn) {
      size_t rbm = (size_t)(b0 + tid) * Tn + t;
      sdt[tid] = tsp[rbm + 1] - tsp[rbm];
    }
    // ---- h(t-1) A-frags: t=0 -> zeros; else gather via relaxed 8B loads ----
    if (t == 0) {
      #pragma unroll
      for (int i = 0; i < 8; ++i) {
        int idx = tid + i * 512;
        int mt = idx >> 10, rr = idx & 1023, ksh = rr >> 6, ln = rr & 63;
        apk[(mt * NKS + 4 + ksh) * 64 + ln] = (short8){0,0,0,0,0,0,0,0};
      }
    } else {
      const unsigned long long* hsrc64 =
          hx64 + ((size_t)((t + 1) & 1) * 2048 + b0) * 128;
      #pragma unroll
      for (int i = 0; i < 8; ++i) {
        int idx = tid + i * 512;                      // 0..4095
        int mt = idx >> 10, rr = idx & 1023, ksh = rr >> 6, ln = rr & 63;
        size_t o = (size_t)(mt * 16 + (ln & 15)) * 128 + ksh * 8 + (ln >> 4) * 2;
        union { unsigned long long u[2]; short8 v; } g;
        g.u[0] = __hip_atomic_load(&hsrc64[o],     __ATOMIC_RELAXED, __HIP_MEMORY_SCOPE_AGENT);
        g.u[1] = __hip_atomic_load(&hsrc64[o + 1], __ATOMIC_RELAXED, __HIP_MEMORY_SCOPE_AGENT);
        apk[(mt * NKS + 4 + ksh) * 64 + ln] = g.v;
      }
    }
    __syncthreads();

    // ---- K-loop: 120 MFMAs/wave, weights in registers, static kh split ----
    floatx4 aR[4], aZ[4], aIN[4], aHN[4];
    #pragma unroll
    for (int mt = 0; mt < 4; ++mt) {
      aR[mt]  = (floatx4){0.f,0.f,0.f,0.f};
      aZ[mt]  = (floatx4){0.f,0.f,0.f,0.f};
      aIN[mt] = (floatx4){0.f,0.f,0.f,0.f};
      aHN[mt] = (floatx4){0.f,0.f,0.f,0.f};
    }
    if (kh == 0) {
      #pragma unroll
      for (int ksl = 0; ksl < 10; ++ksl) {
        short8 A[4];
        #pragma unroll
        for (int mt = 0; mt < 4; ++mt) A[mt] = apk[(mt * NKS + ksl) * 64 + lane];
        #pragma unroll
        for (int mt = 0; mt < 4; ++mt) {
          aR[mt] = __builtin_amdgcn_mfma_f32_16x16x32_bf16(A[mt], Bf[ksl][0], aR[mt], 0, 0, 0);
          aZ[mt] = __builtin_amdgcn_mfma_f32_16x16x32_bf16(A[mt], Bf[ksl][1], aZ[mt], 0, 0, 0);
          if (ksl < 4)
            aIN[mt] = __builtin_amdgcn_mfma_f32_16x16x32_bf16(A[mt], Bf[ksl][2], aIN[mt], 0, 0, 0);
          else
            aHN[mt] = __builtin_amdgcn_mfma_f32_16x16x32_bf16(A[mt], Bf[ksl][2], aHN[mt], 0, 0, 0);
        }
      }
    } else {
      #pragma unroll
      for (int ksl = 0; ksl < 10; ++ksl) {
        short8 A[4];
        #pragma unroll
        for (int mt = 0; mt < 4; ++mt) A[mt] = apk[(mt * NKS + 10 + ksl) * 64 + lane];
        #pragma unroll
        for (int mt = 0; mt < 4; ++mt) {
          aR[mt]  = __builtin_amdgcn_mfma_f32_16x16x32_bf16(A[mt], Bf[ksl][0], aR[mt], 0, 0, 0);
          aZ[mt]  = __builtin_amdgcn_mfma_f32_16x16x32_bf16(A[mt], Bf[ksl][1], aZ[mt], 0, 0, 0);
          aHN[mt] = __builtin_amdgcn_mfma_f32_16x16x32_bf16(A[mt], Bf[ksl][2], aHN[mt], 0, 0, 0);
        }
      }
    }

    // ---- prefetch next step's x ----
    xb[0] += Dn; xb[1] += Dn;
    if (t + 1 < Tn) {
      xp0 = pack8(((const float4*)xb[0])[0], ((const float4*)xb[0])[1]);
      xp1 = pack8(((const float4*)xb[1])[0], ((const float4*)xb[1])[1]);
    }

    // ---- kh=1: publish partial accs ----
    if (kh == 1) {
      #pragma unroll
      for (int mt = 0; mt < 4; ++mt) {
        xacc[(ct * 12 + mt * 3 + 0) * 64 + lane] = aR[mt];
        xacc[(ct * 12 + mt * 3 + 1) * 64 + lane] = aZ[mt];
        xacc[(ct * 12 + mt * 3 + 2) * 64 + lane] = aHN[mt];
      }
    }
    __syncthreads();

    // ---- kh=0: combine halves, gates, h update, decay fold -> hfin ----
    const bool last = (t == Tn - 1);
    if (kh == 0) {
      #pragma unroll
      for (int mt = 0; mt < 4; ++mt) {
        floatx4 R  = aR[mt]  + xacc[(ct * 12 + mt * 3 + 0) * 64 + lane];
        floatx4 Z  = aZ[mt]  + xacc[(ct * 12 + mt * 3 + 1) * 64 + lane];
        floatx4 HN = aHN[mt] + xacc[(ct * 12 + mt * 3 + 2) * 64 + lane];
        #pragma unroll
        for (int q = 0; q < 4; ++q) {
          int m = mt * 16 + quad * 4 + q;
          float r  = sigm(R[q] + bRv);
          float z  = sigm(Z[q] + bZv);
          float nn = tanhfast(aIN[mt][q] + bINv + r * (HN[q] + bHNv));
          float h  = (1.f - z) * nn + z * hfin[m][jl];
          if (!last) {
            float pre = fmaf(sdt[m], wdcv, bdcv);
            h *= frcp(1.f + __expf(pre));              // exp(-softplus(pre))
          }
          hfin[m][jl] = h;
        }
      }
    }

    // ---- cooperative h publish (relaxed 8B stores) + flag release ----
    if (!last) {
      __syncthreads();                                 // hfin complete
      union { unsigned short us[8]; unsigned long long u[2]; } pk2;
      #pragma unroll
      for (int i2 = 0; i2 < 8; ++i2) pk2.us[i2] = f2bf(hfin[pr][pc0 + i2]);
      size_t base = ((size_t)(t & 1) * 2048 + (size_t)(b0 + pr)) * 128
                  + (unsigned)(cc * 64 + pc0) / 4;
      __hip_atomic_store(&hx64[base],     pk2.u[0], __ATOMIC_RELAXED, __HIP_MEMORY_SCOPE_AGENT);
      __hip_atomic_store(&hx64[base + 1], pk2.u[1], __ATOMIC_RELAXED, __HIP_MEMORY_SCOPE_AGENT);
      __syncthreads();                                 // drains vmcnt -> stores ACKed
      if (tid == 0)
        __hip_atomic_store(myflag, t + 1, __ATOMIC_RELAXED, __HIP_MEMORY_SCOPE_AGENT);
    } else {
      __syncthreads();                                 // hfin visible for head
    }
  }

  // ---- head partial: 64-col slice of h_T . W_head ----
  {
    int b = tid >> 3, nt2 = tid & 7;
    float a = 0.f;
    const float* wh = W_head + (size_t)nt2 * Hn + cc * 64;
    #pragma unroll 16
    for (int k2 = 0; k2 < 64; ++k2) a = fmaf(hfin[b][k2], wh[k2], a);
    part[((size_t)cc * 2048 + b0 + b) * 8 + nt2] = a;
  }
}

__global__ __launch_bounds__(256) void cru_head(
    const float* __restrict__ part, const float* __restrict__ b_head,
    float* __restrict__ out)
{
  int i = blockIdx.x * 256 + threadIdx.x;    // 2048*8 = 16384
  if (i >= 2048 * 8) return;
  float a = b_head[i & 7];
  #pragma unroll
  for (int c = 0; c < NC; ++c) a += part[(size_t)c * 16384 + i];
  out[i] = a;
}

extern "C" void kernel_launch(void* const* d_in, const int* in_sizes, int n_in,
                              void* d_out, int out_size, void* d_ws, size_t ws_size,
                              hipStream_t stream)
{
  const float* values  = (const float*)d_in[0];
  const float* mask    = (const float*)d_in[1];
  const float* tsp     = (const float*)d_in[2];
  const float* W_ih    = (const float*)d_in[3];
  const float* W_hh    = (const float*)d_in[4];
  const float* b_ih    = (const float*)d_in[5];
  const float* b_hh    = (const float*)d_in[6];
  const float* W_decay = (const float*)d_in[7];
  const float* b_decay = (const float*)d_in[8];
  const float* W_head  = (const float*)d_in[9];
  const float* b_head  = (const float*)d_in[10];
  float* out = (float*)d_out;

  char* ws = (char*)d_ws;
  short8*             WB   = (short8*)ws;                          // 1.97 MB
  unsigned long long* hx64 = (unsigned long long*)(ws + (2u << 20)); // 4 MB
  float*              part = (float*)(ws + (6u << 20));            // 512 KB
  int*                flgp = (int*)(ws + (6u << 20) + (1u << 19)); // 2 KB

  int nfrag_total = NC * 4 * 2 * 10 * 3 * 64;                      // 122880
  cru_prep<<<(nfrag_total + 255) / 256, 256, 0, stream>>>(W_ih, W_hh, WB);
  cru_zero<<<2, 256, 0, stream>>>(flgp);
  cru_main<<<NC * NGRP, 512, 0, stream>>>(values, mask, tsp, b_ih, b_hh,
      W_decay, b_decay, W_head, WB, hx64, flgp, part);
  cru_head<<<64, 256, 0, stream>>>(part, b_head, out);
}